// Round 9
// baseline (879.624 us; speedup 1.0000x reference)
//
#include <hip/hip_runtime.h>
#include <stdint.h>

typedef _Float16 half_t;
typedef __attribute__((ext_vector_type(4))) _Float16 half4;
typedef __attribute__((ext_vector_type(8))) _Float16 half8;
typedef __attribute__((ext_vector_type(4))) float f32x4;

#define N_TOK 8192
#define H_DIM 1024
#define D_DIM 512
#define NE 8
#define NL 3

#define WAITV6 asm volatile("s_waitcnt vmcnt(6)" ::: "memory")
#define WAITV4 asm volatile("s_waitcnt vmcnt(4)" ::: "memory")
#define WAITV3 asm volatile("s_waitcnt vmcnt(3)" ::: "memory")
#define WAITV0 asm volatile("s_waitcnt vmcnt(0)" ::: "memory")
#define SCHEDB __builtin_amdgcn_sched_barrier(0)
#define RAWBAR __builtin_amdgcn_s_barrier()

// -------- async global->LDS, 16B per lane, linear dest --------
__device__ __forceinline__ void gload_lds16(const half_t* g, half_t* l) {
  __builtin_amdgcn_global_load_lds(
      (const __attribute__((address_space(1))) unsigned int*)g,
      (__attribute__((address_space(3))) unsigned int*)l, 16, 0, 0);
}

// -------- 256-thread 64x64 transpose+cvt tile (tile pitch 65 floats) --------
__device__ __forceinline__ void tr_tile_256(
    const float* src, half_t* oh, half_t* ol, int R, int C,
    int bx, int by, int tid, float* tile) {
  const int rt = bx * 64, ct = by * 64;
  const int r = tid >> 2, c0 = (tid & 3) * 16;
  const float* p = src + (size_t)(rt + r) * C + ct + c0;
#pragma unroll
  for (int q = 0; q < 4; ++q) {
    float4 v = *(const float4*)(p + q * 4);
    tile[r * 65 + c0 + q * 4 + 0] = v.x;
    tile[r * 65 + c0 + q * 4 + 1] = v.y;
    tile[r * 65 + c0 + q * 4 + 2] = v.z;
    tile[r * 65 + c0 + q * 4 + 3] = v.w;
  }
  __syncthreads();
  const int nl = tid >> 2, k0 = (tid & 3) * 16;
  half8 hv0, hv1, lv0, lv1;
#pragma unroll
  for (int i = 0; i < 16; ++i) {
    float v = tile[(k0 + i) * 65 + nl];
    half_t h = (half_t)v;
    half_t lo = (half_t)((v - (float)h) * 2048.f);
    if (i < 8) { hv0[i] = h; lv0[i] = lo; } else { hv1[i - 8] = h; lv1[i - 8] = lo; }
  }
  half_t* dst = oh + (size_t)(ct + nl) * R + rt + k0;
  *(half8*)dst = hv0;
  *(half8*)(dst + 8) = hv1;
  if (ol) {
    half_t* dl = ol + (size_t)(ct + nl) * R + rt + k0;
    *(half8*)dl = lv0;
    *(half8*)(dl + 8) = lv1;
  }
}

// -------- prep: init + w1 transpose + W[0] transpose + cvt_x, one kernel --------
__global__ __launch_bounds__(256) void prep(
    const float* __restrict__ hww, float* __restrict__ hwp,
    int* __restrict__ cnt, int* __restrict__ done,
    const float* __restrict__ w1, half_t* __restrict__ w1th, half_t* __restrict__ w1tl,
    const float* __restrict__ Wb0, half_t* __restrict__ Wth0, half_t* __restrict__ Wtl0,
    const float* __restrict__ hs, half_t* __restrict__ xh0, half_t* __restrict__ xl0) {
  __shared__ float tile[64 * 65];
  const int bid = blockIdx.x, tid = threadIdx.x;
  if (bid == 0) {
    if (tid < NL * NE) cnt[tid] = 0;
    if (tid < NL) done[tid] = 0;
    if (tid == 0) {
      float m = fmaxf(fmaxf(hww[0], hww[1]), hww[2]);
      float e0 = expf(hww[0] - m), e1 = expf(hww[1] - m), e2 = expf(hww[2] - m);
      float s = e0 + e1 + e2;
      hwp[0] = e0 / s; hwp[1] = e1 / s; hwp[2] = e2 / s;
    }
    return;
  }
  if (bid < 385) {
    const int t = bid - 1;
    const int bx = t & 15, by = (t >> 4) & 7, bz = t >> 7;
    tr_tile_256(w1 + (size_t)bz * H_DIM * D_DIM,
                w1th + (size_t)bz * D_DIM * H_DIM,
                w1tl + (size_t)bz * D_DIM * H_DIM,
                H_DIM, D_DIM, bx, by, tid, tile);
    return;
  }
  if (bid < 2433) {
    const int t = bid - 385;
    const int bx = t & 15, by = (t >> 4) & 15, bz = t >> 8;
    tr_tile_256(Wb0 + (size_t)bz * H_DIM * H_DIM,
                Wth0 + (size_t)bz * H_DIM * H_DIM,
                Wtl0 + (size_t)bz * H_DIM * H_DIM,
                H_DIM, H_DIM, bx, by, tid, tile);
    return;
  }
  int i = (bid - 2433) * 256 + tid;
  const int total = N_TOK * H_DIM / 4, stride = 1024 * 256;
  for (; i < total; i += stride) {
    float4 v = ((const float4*)hs)[i];
    float vv[4] = {v.x, v.y, v.z, v.w};
    half4 hv, lv;
#pragma unroll
    for (int j = 0; j < 4; ++j) {
      half_t h = (half_t)vv[j];
      hv[j] = h;
      lv[j] = (half_t)((vv[j] - (float)h) * 2048.f);
    }
    ((half4*)xh0)[i] = hv;
    ((half4*)xl0)[i] = lv;
  }
}

// -------- router GEMM: h = relu(x @ w1 + b1), fp16-split 3-pass MFMA --------
// BM=128 BN=128 BK=32, 512 thr (8 waves 2x4), 2-buf counted vmcnt, swizzled LDS.
__global__ __launch_bounds__(512, 4) void routing_gemm(
    const half_t* __restrict__ xh, const half_t* __restrict__ xl,
    const half_t* __restrict__ wh, const half_t* __restrict__ wl,
    const float* __restrict__ b1, float* __restrict__ hout) {
  __shared__ __align__(16) half_t lds[2 * 16384];
  const int tid = threadIdx.x;
  const int lane = tid & 63, wv = tid >> 6;
  const int wm = wv >> 2, wn = wv & 3;
  const int lid = ((int)blockIdx.x & 7) * 32 + ((int)blockIdx.x >> 3);
  const int nt = lid & 3, mt = lid >> 2;

  const int srow = tid >> 2;
  const int skc = (((tid & 3) ^ ((tid >> 2) & 3) ^ ((tid >> 4) & 3)) * 8);
  const half_t* gAh = xh + (size_t)(mt * 128 + srow) * H_DIM + skc;
  const half_t* gAl = xl + (size_t)(mt * 128 + srow) * H_DIM + skc;
  const half_t* gBh = wh + (size_t)(nt * 128 + srow) * H_DIM + skc;
  const half_t* gBl = wl + (size_t)(nt * 128 + srow) * H_DIM + skc;

  f32x4 accM[4][2], accX[4][2];
#pragma unroll
  for (int m = 0; m < 4; ++m)
#pragma unroll
    for (int n = 0; n < 2; ++n) {
      accM[m][n] = {0.f, 0.f, 0.f, 0.f};
      accX[m][n] = {0.f, 0.f, 0.f, 0.f};
    }

  const int fr = lane & 15, fg = lane >> 4;
  const int fgs = fg ^ ((fr & 3) ^ ((fr >> 2) & 3));
  const int aoff = (wm * 64 + fr) * 32 + fgs * 8;
  const int boff = 8192 + (wn * 32 + fr) * 32 + fgs * 8;

#define R_STAGE(bo, kk) do { \
    const int go_ = (kk) * 32; \
    gload_lds16(gAh + go_, lds + (bo) + tid * 8); \
    gload_lds16(gAl + go_, lds + (bo) + 4096 + tid * 8); \
    gload_lds16(gBh + go_, lds + (bo) + 8192 + tid * 8); \
    gload_lds16(gBl + go_, lds + (bo) + 12288 + tid * 8); \
  } while (0)

  R_STAGE(0, 0);
  for (int k = 0; k < 32; ++k) {
    if (k + 1 < 32) R_STAGE(((k + 1) & 1) * 16384, k + 1);
    if (k < 31) { WAITV4; } else { WAITV0; }
    SCHEDB;
    RAWBAR;
    SCHEDB;
    const int cb = (k & 1) * 16384;
    half8 a_h[4], a_l[4], b_h[2], b_l[2];
#pragma unroll
    for (int m = 0; m < 4; ++m) {
      a_h[m] = *(const half8*)&lds[cb + aoff + m * 512];
      a_l[m] = *(const half8*)&lds[cb + 4096 + aoff + m * 512];
    }
#pragma unroll
    for (int n = 0; n < 2; ++n) {
      b_h[n] = *(const half8*)&lds[cb + boff + n * 512];
      b_l[n] = *(const half8*)&lds[cb + 4096 + boff + n * 512];
    }
    __builtin_amdgcn_s_setprio(1);
#pragma unroll
    for (int m = 0; m < 4; ++m)
#pragma unroll
      for (int n = 0; n < 2; ++n) {
        accM[m][n] = __builtin_amdgcn_mfma_f32_16x16x32_f16(a_h[m], b_h[n], accM[m][n], 0, 0, 0);
        accX[m][n] = __builtin_amdgcn_mfma_f32_16x16x32_f16(a_h[m], b_l[n], accX[m][n], 0, 0, 0);
        accX[m][n] = __builtin_amdgcn_mfma_f32_16x16x32_f16(a_l[m], b_h[n], accX[m][n], 0, 0, 0);
      }
    __builtin_amdgcn_s_setprio(0);
    SCHEDB;
    RAWBAR;
    SCHEDB;
  }
#undef R_STAGE

  const float inv = 1.0f / 2048.0f;
#pragma unroll
  for (int m = 0; m < 4; ++m) {
    const int row0 = mt * 128 + wm * 64 + m * 16 + fg * 4;
#pragma unroll
    for (int n = 0; n < 2; ++n) {
      const int col = nt * 128 + wn * 32 + n * 16 + fr;
      const float bv = b1[col];
#pragma unroll
      for (int r = 0; r < 4; ++r) {
        float v = accM[m][n][r] + accX[m][n][r] * inv + bv;
        hout[(size_t)(row0 + r) * D_DIM + col] = fmaxf(v, 0.f);
      }
    }
  }
}

// -------- logits + argmax + per-expert count; last block scans --------
__global__ void logits_argmax(const float* __restrict__ hbuf, const float* __restrict__ w2,
                              const float* __restrict__ b2, int* __restrict__ eidx,
                              int* __restrict__ cnt, int* __restrict__ done,
                              int* __restrict__ offs, int* __restrict__ cur) {
  const int tid = threadIdx.x, lane = tid & 63, wv = tid >> 6;
  const int t = blockIdx.x * 4 + wv;
  const float* hr = hbuf + (size_t)t * D_DIM;
  float4 h0 = *(const float4*)(hr + lane * 8);
  float4 h1 = *(const float4*)(hr + lane * 8 + 4);
  float p[8] = {0, 0, 0, 0, 0, 0, 0, 0};
  const float* wr = w2 + (size_t)lane * 8 * 8;
  float hv[8] = {h0.x, h0.y, h0.z, h0.w, h1.x, h1.y, h1.z, h1.w};
#pragma unroll
  for (int j = 0; j < 8; ++j) {
    float4 wa = *(const float4*)(wr + j * 8);
    float4 wb = *(const float4*)(wr + j * 8 + 4);
    p[0] += hv[j] * wa.x; p[1] += hv[j] * wa.y; p[2] += hv[j] * wa.z; p[3] += hv[j] * wa.w;
    p[4] += hv[j] * wb.x; p[5] += hv[j] * wb.y; p[6] += hv[j] * wb.z; p[7] += hv[j] * wb.w;
  }
#pragma unroll
  for (int o = 32; o > 0; o >>= 1) {
#pragma unroll
    for (int e = 0; e < 8; ++e) p[e] += __shfl_xor(p[e], o, 64);
  }
  if (lane == 0) {
    int best = 0;
    float bvv = p[0] + b2[0];
#pragma unroll
    for (int e = 1; e < 8; ++e) {
      float v = p[e] + b2[e];
      if (v > bvv) { bvv = v; best = e; }
    }
    eidx[t] = best;
    atomicAdd(&cnt[best], 1);
  }
  __syncthreads();
  if (tid == 0) {
    __threadfence();
    int tix = atomicAdd(done, 1);
    if (tix == (int)gridDim.x - 1) {
      int a = 0;
#pragma unroll
      for (int i = 0; i < 8; ++i) { offs[i] = a; cur[i] = a; a += cnt[i]; }
      offs[8] = a;
      __threadfence();
    }
  }
}

__global__ void scatter_perm(const int* __restrict__ eidx, int* __restrict__ cur,
                             int* __restrict__ perm) {
  int t = blockIdx.x * blockDim.x + threadIdx.x;
  if (t < N_TOK) {
    int p = atomicAdd(&cur[eidx[t]], 1);
    perm[p] = t;
  }
}

// -------- expert GEMM, BM=256 BN=128 BK=32, 512 thr (8 waves 4x2) --------
// wave-tile 64x64 (4x4 frags). 2-buf counted vmcnt, swizzled LDS.
// SPLIT=1: 3-pass fp16-split; epilogue writes ONLY next-level x hi/lo.
// SPLIT=0 (last level): 1-pass; epilogue writes dout = hw0*x1h + hw1*x(=xh) + hw2*out.
// Blocks [0,312)=GEMM; [312,2360)=transpose of next level's W (FUSET=1).
// SPLIT=1 LDS buf (elems): Ah[0,8192) Al[8192,16384) Bh[16384,20480) Bl[20480,24576)
// SPLIT=0 LDS buf: Ah[0,8192) Bh[8192,12288)
template <int SPLIT, int FUSET>
__global__ __launch_bounds__(512, 2) void expert_gemm(
    const half_t* __restrict__ xh, const half_t* __restrict__ xl,
    const half_t* __restrict__ Wth, const half_t* __restrict__ Wtl,
    const float* __restrict__ bb, const float* __restrict__ asg,
    const int* __restrict__ perm, const int* __restrict__ offs,
    const float* __restrict__ hwp,
    float* __restrict__ dout, const half_t* __restrict__ x1h,
    half_t* __restrict__ xnh, half_t* __restrict__ xnl,
    const float* __restrict__ WbN, half_t* __restrict__ WthN, half_t* __restrict__ WtlN) {
  constexpr int BUF = SPLIT ? 24576 : 12288;
  constexpr int OBH = SPLIT ? 16384 : 8192;
  __shared__ __align__(16) half_t lds[2 * BUF];
  __shared__ int toks[256];
  const int tid = threadIdx.x;

  if (FUSET && (int)blockIdx.x >= 312) {
    // 512-thread 64x64 transpose+cvt of next level's W_base
    float* tile = (float*)lds;  // [64][65]
    const int tb = (int)blockIdx.x - 312;
    const int bx = tb & 15, by = (tb >> 4) & 15, bz = tb >> 8;
    const size_t zo = (size_t)bz * H_DIM * H_DIM;
    const int rt = bx * 64, ct = by * 64;
    const int r = tid >> 3, c0 = (tid & 7) * 8;
    const float* p = WbN + zo + (size_t)(rt + r) * H_DIM + ct + c0;
    float4 va = *(const float4*)p;
    float4 vb = *(const float4*)(p + 4);
    tile[r * 65 + c0 + 0] = va.x; tile[r * 65 + c0 + 1] = va.y;
    tile[r * 65 + c0 + 2] = va.z; tile[r * 65 + c0 + 3] = va.w;
    tile[r * 65 + c0 + 4] = vb.x; tile[r * 65 + c0 + 5] = vb.y;
    tile[r * 65 + c0 + 6] = vb.z; tile[r * 65 + c0 + 7] = vb.w;
    __syncthreads();
    const int nl = tid >> 3, k0 = (tid & 7) * 8;
    half8 hvv, lvv;
#pragma unroll
    for (int i = 0; i < 8; ++i) {
      float v = tile[(k0 + i) * 65 + nl];
      half_t h = (half_t)v;
      hvv[i] = h;
      lvv[i] = (half_t)((v - (float)h) * 2048.f);
    }
    half_t* dst = WthN + zo + (size_t)(ct + nl) * H_DIM + rt + k0;
    *(half8*)dst = hvv;
    if (WtlN) {
      half_t* dl = WtlN + zo + (size_t)(ct + nl) * H_DIM + rt + k0;
      *(half8*)dl = lvv;
    }
    return;
  }

  // ---- GEMM: bid in [0,312), XCD-chunked (39 lids/XCD), N-fastest ----
  const int lid = ((int)blockIdx.x & 7) * 39 + ((int)blockIdx.x >> 3);
  const int byn = lid & 7;    // N-tile 0..7 (128 cols each)
  const int bxt = lid >> 3;   // M-tile 0..38 (256 rows each)
  int e = -1, base = 0, nrows = 0, acc_t = 0;
#pragma unroll
  for (int i = 0; i < 8; ++i) {
    int s = offs[i], t2 = offs[i + 1];
    int ntl = (t2 - s + 255) >> 8;
    if (e < 0 && bxt < acc_t + ntl) {
      e = i;
      base = s + (bxt - acc_t) * 256;
      nrows = t2 - base;
      if (nrows > 256) nrows = 256;
    }
    acc_t += ntl;
  }
  if (e < 0) return;
  if (tid < 256) toks[tid] = (tid < nrows) ? perm[base + tid] : perm[base];
  __syncthreads();
  const int srow = tid >> 2;  // 0..127
  const int skc = (((tid & 3) ^ ((tid >> 2) & 3) ^ ((tid >> 4) & 3)) * 8);
  const int tokA0 = toks[srow];
  const int tokA1 = toks[128 + srow];
  const half_t* gAh0 = xh + (size_t)tokA0 * H_DIM + skc;
  const half_t* gAh1 = xh + (size_t)tokA1 * H_DIM + skc;
  const half_t* gAl0 = SPLIT ? (xl + (size_t)tokA0 * H_DIM + skc) : nullptr;
  const half_t* gAl1 = SPLIT ? (xl + (size_t)tokA1 * H_DIM + skc) : nullptr;
  const size_t bg = (size_t)e * H_DIM * H_DIM + (size_t)(byn * 128 + srow) * H_DIM + skc;
  const half_t* gBh = Wth + bg;
  const half_t* gBl = SPLIT ? (Wtl + bg) : nullptr;

  f32x4 accM[4][4], accX[4][4];
#pragma unroll
  for (int m = 0; m < 4; ++m)
#pragma unroll
    for (int n = 0; n < 4; ++n) {
      accM[m][n] = {0.f, 0.f, 0.f, 0.f};
      accX[m][n] = {0.f, 0.f, 0.f, 0.f};
    }

  const int lane = tid & 63, wv = tid >> 6, wm = wv >> 1, wn = wv & 1;
  const int fr = lane & 15, fg = lane >> 4;
  const int fgs = fg ^ ((fr & 3) ^ ((fr >> 2) & 3));
  const int aoff = (wm * 64 + fr) * 32 + fgs * 8;
  const int boff = OBH + (wn * 64 + fr) * 32 + fgs * 8;

#define E_STAGE(bo, kk) do { \
    const int go_ = (kk) * 32; \
    gload_lds16(gAh0 + go_, lds + (bo) + tid * 8); \
    gload_lds16(gAh1 + go_, lds + (bo) + 4096 + tid * 8); \
    gload_lds16(gBh + go_, lds + (bo) + OBH + tid * 8); \
    if (SPLIT) { \
      gload_lds16(gAl0 + go_, lds + (bo) + 8192 + tid * 8); \
      gload_lds16(gAl1 + go_, lds + (bo) + 8192 + 4096 + tid * 8); \
      gload_lds16(gBl + go_, lds + (bo) + OBH + 4096 + tid * 8); \
    } \
  } while (0)

  E_STAGE(0, 0);
  for (int k = 0; k < 32; ++k) {
    if (k + 1 < 32) E_STAGE(((k + 1) & 1) * BUF, k + 1);
    if (k < 31) { if (SPLIT) { WAITV6; } else { WAITV3; } } else { WAITV0; }
    SCHEDB;
    RAWBAR;
    SCHEDB;
    const int cb = (k & 1) * BUF;
    half8 a_h[4], b_h[4], a_l[4], b_l[4];
#pragma unroll
    for (int m = 0; m < 4; ++m) {
      a_h[m] = *(const half8*)&lds[cb + aoff + m * 512];
      if (SPLIT) a_l[m] = *(const half8*)&lds[cb + 8192 + aoff + m * 512];
    }
#pragma unroll
    for (int n = 0; n < 4; ++n) {
      b_h[n] = *(const half8*)&lds[cb + boff + n * 512];
      if (SPLIT) b_l[n] = *(const half8*)&lds[cb + 4096 + boff + n * 512];
    }
    __builtin_amdgcn_s_setprio(1);
#pragma unroll
    for (int m = 0; m < 4; ++m)
#pragma unroll
      for (int n = 0; n < 4; ++n) {
        accM[m][n] = __builtin_amdgcn_mfma_f32_16x16x32_f16(a_h[m], b_h[n], accM[m][n], 0, 0, 0);
        if (SPLIT) {
          accX[m][n] = __builtin_amdgcn_mfma_f32_16x16x32_f16(a_h[m], b_l[n], accX[m][n], 0, 0, 0);
          accX[m][n] = __builtin_amdgcn_mfma_f32_16x16x32_f16(a_l[m], b_h[n], accX[m][n], 0, 0, 0);
        }
      }
    __builtin_amdgcn_s_setprio(0);
    SCHEDB;
    RAWBAR;
    SCHEDB;
  }
#undef E_STAGE

  const float ae = asg[e];
  const float hw0 = hwp[0], hw1 = hwp[1], hw2 = hwp[2];
  const float inv = 1.0f / 2048.0f;
#pragma unroll
  for (int m = 0; m < 4; ++m) {
    const int rl0 = wm * 64 + m * 16 + fg * 4;
#pragma unroll
    for (int n = 0; n < 4; ++n) {
      const int col = byn * 128 + wn * 64 + n * 16 + fr;
      const float bbv = bb[(size_t)e * H_DIM + col];
#pragma unroll
      for (int r = 0; r < 4; ++r) {
        const int rl = rl0 + r;
        if (rl < nrows) {
          const int tok = toks[rl];
          float s = accM[m][n][r] + bbv;
          if (SPLIT) s += accX[m][n][r] * inv;
          const float o = ae * s;
          const size_t idx = (size_t)tok * H_DIM + col;
          if (SPLIT) {
            half_t hv = (half_t)o;
            xnh[idx] = hv;
            xnl[idx] = (half_t)((o - (float)hv) * 2048.f);
          } else {
            dout[idx] = hw0 * (float)x1h[idx] + hw1 * (float)xh[idx] + hw2 * o;
          }
        }
      }
    }
  }
}

extern "C" void kernel_launch(void* const* d_in, const int* in_sizes, int n_in,
                              void* d_out, int out_size, void* d_ws, size_t ws_size,
                              hipStream_t stream) {
  const float* hs  = (const float*)d_in[0];   // (2,4096,1024)
  const float* w1  = (const float*)d_in[1];   // (3,1024,512)
  const float* b1  = (const float*)d_in[2];   // (3,512)
  const float* w2  = (const float*)d_in[3];   // (3,512,8)
  const float* b2  = (const float*)d_in[4];   // (3,8)
  const float* lea = (const float*)d_in[5];   // (3,8)
  const float* hww = (const float*)d_in[6];   // (3,)
  const float* Wb  = (const float*)d_in[7];   // (3,8,1024,1024)
  const float* bb  = (const float*)d_in[8];   // (3,8,1024)
  float* outp = (float*)d_out;

  char* ws = (char*)d_ws;
  size_t off = 0;
  half_t* WthA = (half_t*)(ws + off); off += (size_t)NE * H_DIM * H_DIM * 2;
  half_t* WtlA = (half_t*)(ws + off); off += (size_t)NE * H_DIM * H_DIM * 2;
  half_t* WthB = (half_t*)(ws + off); off += (size_t)NE * H_DIM * H_DIM * 2;
  half_t* WtlB = (half_t*)(ws + off); off += (size_t)NE * H_DIM * H_DIM * 2;
  half_t* w1th = (half_t*)(ws + off); off += (size_t)NL * D_DIM * H_DIM * 2;
  half_t* w1tl = (half_t*)(ws + off); off += (size_t)NL * D_DIM * H_DIM * 2;
  half_t* xh0  = (half_t*)(ws + off); off += (size_t)N_TOK * H_DIM * 2;
  half_t* xl0  = (half_t*)(ws + off); off += (size_t)N_TOK * H_DIM * 2;
  half_t* xh1  = (half_t*)(ws + off); off += (size_t)N_TOK * H_DIM * 2;
  half_t* xl1  = (half_t*)(ws + off); off += (size_t)N_TOK * H_DIM * 2;
  float*  hbuf = (float*)(ws + off);  off += (size_t)N_TOK * D_DIM * 4;
  int*    eidx = (int*)(ws + off);    off += (size_t)N_TOK * 4;
  int*    perm = (int*)(ws + off);    off += (size_t)N_TOK * 4;
  int*    cnt  = (int*)(ws + off);    off += (size_t)NL * NE * 4;
  int*    offs = (int*)(ws + off);    off += (size_t)NL * (NE + 1) * 4;
  int*    cur  = (int*)(ws + off);    off += (size_t)NL * NE * 4;
  int*    done = (int*)(ws + off);    off += (size_t)NL * 4;
  float*  hwp  = (float*)(ws + off);  off += 16;

  prep<<<3457, 256, 0, stream>>>(hww, hwp, cnt, done, w1, w1th, w1tl,
                                 Wb, WthA, WtlA, hs, xh0, xl0);

  for (int l = 0; l < NL; ++l) {
    const half_t* xch = (l & 1) ? xh1 : xh0;
    const half_t* xcl = (l & 1) ? xl1 : xl0;
    half_t* xnh = (l & 1) ? xh0 : xh1;
    half_t* xnl = (l & 1) ? xl0 : xl1;
    routing_gemm<<<256, 512, 0, stream>>>(
        xch, xcl, w1th + (size_t)l * D_DIM * H_DIM, w1tl + (size_t)l * D_DIM * H_DIM,
        b1 + l * D_DIM, hbuf);
    logits_argmax<<<N_TOK / 4, 256, 0, stream>>>(
        hbuf, w2 + (size_t)l * D_DIM * NE, b2 + l * NE, eidx,
        cnt + l * NE, done + l, offs + l * (NE + 1), cur + l * NE);
    scatter_perm<<<N_TOK / 256, 256, 0, stream>>>(eidx, cur + l * NE, perm);
    if (l == 0) {
      expert_gemm<1, 1><<<2360, 512, 0, stream>>>(
          xch, xcl, WthA, WtlA, bb + (size_t)l * NE * H_DIM,
          lea + l * NE, perm, offs + l * (NE + 1), hwp,
          (float*)nullptr, (const half_t*)nullptr, xnh, xnl,
          Wb + (size_t)1 * NE * H_DIM * H_DIM, WthB, WtlB);
    } else if (l == 1) {
      expert_gemm<1, 1><<<2360, 512, 0, stream>>>(
          xch, xcl, WthB, WtlB, bb + (size_t)l * NE * H_DIM,
          lea + l * NE, perm, offs + l * (NE + 1), hwp,
          (float*)nullptr, (const half_t*)nullptr, xnh, xnl,
          Wb + (size_t)2 * NE * H_DIM * H_DIM, WthA, (half_t*)nullptr);
    } else {
      // last level: xch = x2 (xh0); x1 hi lives in xh1
      expert_gemm<0, 0><<<312, 512, 0, stream>>>(
          xch, (const half_t*)nullptr, WthA, (const half_t*)nullptr,
          bb + (size_t)l * NE * H_DIM,
          lea + l * NE, perm, offs + l * (NE + 1), hwp,
          outp, xh1, (half_t*)nullptr, (half_t*)nullptr,
          (const float*)nullptr, (half_t*)nullptr, (half_t*)nullptr);
    }
  }
}

// Round 10
// 820.023 us; speedup vs baseline: 1.0727x; 1.0727x over previous
//
#include <hip/hip_runtime.h>
#include <stdint.h>

typedef _Float16 half_t;
typedef __attribute__((ext_vector_type(4))) _Float16 half4;
typedef __attribute__((ext_vector_type(8))) _Float16 half8;
typedef __attribute__((ext_vector_type(4))) float f32x4;

#define N_TOK 8192
#define H_DIM 1024
#define D_DIM 512
#define NE 8
#define NL 3

#define WAITV4 asm volatile("s_waitcnt vmcnt(4)" ::: "memory")
#define WAITV2 asm volatile("s_waitcnt vmcnt(2)" ::: "memory")
#define WAITV0 asm volatile("s_waitcnt vmcnt(0)" ::: "memory")
#define SCHEDB __builtin_amdgcn_sched_barrier(0)
#define RAWBAR __builtin_amdgcn_s_barrier()

// -------- async global->LDS, 16B per lane, linear dest --------
__device__ __forceinline__ void gload_lds16(const half_t* g, half_t* l) {
  __builtin_amdgcn_global_load_lds(
      (const __attribute__((address_space(1))) unsigned int*)g,
      (__attribute__((address_space(3))) unsigned int*)l, 16, 0, 0);
}

// -------- 256-thread 64x64 transpose+cvt tile (tile pitch 65 floats) --------
__device__ __forceinline__ void tr_tile_256(
    const float* src, half_t* oh, half_t* ol, int R, int C,
    int bx, int by, int tid, float* tile) {
  const int rt = bx * 64, ct = by * 64;
  const int r = tid >> 2, c0 = (tid & 3) * 16;
  const float* p = src + (size_t)(rt + r) * C + ct + c0;
#pragma unroll
  for (int q = 0; q < 4; ++q) {
    float4 v = *(const float4*)(p + q * 4);
    tile[r * 65 + c0 + q * 4 + 0] = v.x;
    tile[r * 65 + c0 + q * 4 + 1] = v.y;
    tile[r * 65 + c0 + q * 4 + 2] = v.z;
    tile[r * 65 + c0 + q * 4 + 3] = v.w;
  }
  __syncthreads();
  const int nl = tid >> 2, k0 = (tid & 3) * 16;
  half8 hv0, hv1, lv0, lv1;
#pragma unroll
  for (int i = 0; i < 16; ++i) {
    float v = tile[(k0 + i) * 65 + nl];
    half_t h = (half_t)v;
    half_t lo = (half_t)((v - (float)h) * 2048.f);
    if (i < 8) { hv0[i] = h; lv0[i] = lo; } else { hv1[i - 8] = h; lv1[i - 8] = lo; }
  }
  half_t* dst = oh + (size_t)(ct + nl) * R + rt + k0;
  *(half8*)dst = hv0;
  *(half8*)(dst + 8) = hv1;
  if (ol) {
    half_t* dl = ol + (size_t)(ct + nl) * R + rt + k0;
    *(half8*)dl = lv0;
    *(half8*)(dl + 8) = lv1;
  }
}

// -------- prep: init + w1 transpose + W[0] transpose + cvt_x, one kernel --------
__global__ __launch_bounds__(256) void prep(
    const float* __restrict__ hww, float* __restrict__ hwp,
    int* __restrict__ cnt, int* __restrict__ done,
    const float* __restrict__ w1, half_t* __restrict__ w1th, half_t* __restrict__ w1tl,
    const float* __restrict__ Wb0, half_t* __restrict__ Wth0, half_t* __restrict__ Wtl0,
    const float* __restrict__ hs, half_t* __restrict__ xh0, half_t* __restrict__ xl0) {
  __shared__ float tile[64 * 65];
  const int bid = blockIdx.x, tid = threadIdx.x;
  if (bid == 0) {
    if (tid < NL * NE) cnt[tid] = 0;
    if (tid < NL) done[tid] = 0;
    if (tid == 0) {
      float m = fmaxf(fmaxf(hww[0], hww[1]), hww[2]);
      float e0 = expf(hww[0] - m), e1 = expf(hww[1] - m), e2 = expf(hww[2] - m);
      float s = e0 + e1 + e2;
      hwp[0] = e0 / s; hwp[1] = e1 / s; hwp[2] = e2 / s;
    }
    return;
  }
  if (bid < 385) {
    const int t = bid - 1;
    const int bx = t & 15, by = (t >> 4) & 7, bz = t >> 7;
    tr_tile_256(w1 + (size_t)bz * H_DIM * D_DIM,
                w1th + (size_t)bz * D_DIM * H_DIM,
                w1tl + (size_t)bz * D_DIM * H_DIM,
                H_DIM, D_DIM, bx, by, tid, tile);
    return;
  }
  if (bid < 2433) {
    const int t = bid - 385;
    const int bx = t & 15, by = (t >> 4) & 15, bz = t >> 8;
    tr_tile_256(Wb0 + (size_t)bz * H_DIM * H_DIM,
                Wth0 + (size_t)bz * H_DIM * H_DIM,
                Wtl0 + (size_t)bz * H_DIM * H_DIM,
                H_DIM, H_DIM, bx, by, tid, tile);
    return;
  }
  int i = (bid - 2433) * 256 + tid;
  const int total = N_TOK * H_DIM / 4, stride = 1024 * 256;
  for (; i < total; i += stride) {
    float4 v = ((const float4*)hs)[i];
    float vv[4] = {v.x, v.y, v.z, v.w};
    half4 hv, lv;
#pragma unroll
    for (int j = 0; j < 4; ++j) {
      half_t h = (half_t)vv[j];
      hv[j] = h;
      lv[j] = (half_t)((vv[j] - (float)h) * 2048.f);
    }
    ((half4*)xh0)[i] = hv;
    ((half4*)xl0)[i] = lv;
  }
}

// -------- router GEMM: h = relu(x @ w1 + b1), fp16-split 3-pass MFMA --------
// BM=128 BN=128 BK=32, 512 thr (8 waves 2x4), 2-buf counted vmcnt, swizzled LDS.
__global__ __launch_bounds__(512, 4) void routing_gemm(
    const half_t* __restrict__ xh, const half_t* __restrict__ xl,
    const half_t* __restrict__ wh, const half_t* __restrict__ wl,
    const float* __restrict__ b1, float* __restrict__ hout) {
  __shared__ __align__(16) half_t lds[2 * 16384];
  const int tid = threadIdx.x;
  const int lane = tid & 63, wv = tid >> 6;
  const int wm = wv >> 2, wn = wv & 3;
  const int lid = ((int)blockIdx.x & 7) * 32 + ((int)blockIdx.x >> 3);
  const int nt = lid & 3, mt = lid >> 2;

  const int srow = tid >> 2;
  const int skc = (((tid & 3) ^ ((tid >> 2) & 3) ^ ((tid >> 4) & 3)) * 8);
  const half_t* gAh = xh + (size_t)(mt * 128 + srow) * H_DIM + skc;
  const half_t* gAl = xl + (size_t)(mt * 128 + srow) * H_DIM + skc;
  const half_t* gBh = wh + (size_t)(nt * 128 + srow) * H_DIM + skc;
  const half_t* gBl = wl + (size_t)(nt * 128 + srow) * H_DIM + skc;

  f32x4 accM[4][2], accX[4][2];
#pragma unroll
  for (int m = 0; m < 4; ++m)
#pragma unroll
    for (int n = 0; n < 2; ++n) {
      accM[m][n] = {0.f, 0.f, 0.f, 0.f};
      accX[m][n] = {0.f, 0.f, 0.f, 0.f};
    }

  const int fr = lane & 15, fg = lane >> 4;
  const int fgs = fg ^ ((fr & 3) ^ ((fr >> 2) & 3));
  const int aoff = (wm * 64 + fr) * 32 + fgs * 8;
  const int boff = 8192 + (wn * 32 + fr) * 32 + fgs * 8;

#define R_STAGE(bo, kk) do { \
    const int go_ = (kk) * 32; \
    gload_lds16(gAh + go_, lds + (bo) + tid * 8); \
    gload_lds16(gAl + go_, lds + (bo) + 4096 + tid * 8); \
    gload_lds16(gBh + go_, lds + (bo) + 8192 + tid * 8); \
    gload_lds16(gBl + go_, lds + (bo) + 12288 + tid * 8); \
  } while (0)

  R_STAGE(0, 0);
  for (int k = 0; k < 32; ++k) {
    if (k + 1 < 32) R_STAGE(((k + 1) & 1) * 16384, k + 1);
    if (k < 31) { WAITV4; } else { WAITV0; }
    SCHEDB;
    RAWBAR;
    SCHEDB;
    const int cb = (k & 1) * 16384;
    half8 a_h[4], a_l[4], b_h[2], b_l[2];
#pragma unroll
    for (int m = 0; m < 4; ++m) {
      a_h[m] = *(const half8*)&lds[cb + aoff + m * 512];
      a_l[m] = *(const half8*)&lds[cb + 4096 + aoff + m * 512];
    }
#pragma unroll
    for (int n = 0; n < 2; ++n) {
      b_h[n] = *(const half8*)&lds[cb + boff + n * 512];
      b_l[n] = *(const half8*)&lds[cb + 4096 + boff + n * 512];
    }
    __builtin_amdgcn_s_setprio(1);
#pragma unroll
    for (int m = 0; m < 4; ++m)
#pragma unroll
      for (int n = 0; n < 2; ++n) {
        accM[m][n] = __builtin_amdgcn_mfma_f32_16x16x32_f16(a_h[m], b_h[n], accM[m][n], 0, 0, 0);
        accX[m][n] = __builtin_amdgcn_mfma_f32_16x16x32_f16(a_h[m], b_l[n], accX[m][n], 0, 0, 0);
        accX[m][n] = __builtin_amdgcn_mfma_f32_16x16x32_f16(a_l[m], b_h[n], accX[m][n], 0, 0, 0);
      }
    __builtin_amdgcn_s_setprio(0);
    SCHEDB;
    RAWBAR;
    SCHEDB;
  }
#undef R_STAGE

  const float inv = 1.0f / 2048.0f;
#pragma unroll
  for (int m = 0; m < 4; ++m) {
    const int row0 = mt * 128 + wm * 64 + m * 16 + fg * 4;
#pragma unroll
    for (int n = 0; n < 2; ++n) {
      const int col = nt * 128 + wn * 32 + n * 16 + fr;
      const float bv = b1[col];
#pragma unroll
      for (int r = 0; r < 4; ++r) {
        float v = accM[m][n][r] + accX[m][n][r] * inv + bv;
        hout[(size_t)(row0 + r) * D_DIM + col] = fmaxf(v, 0.f);
      }
    }
  }
}

// -------- logits + argmax + per-expert count; last block scans --------
__global__ void logits_argmax(const float* __restrict__ hbuf, const float* __restrict__ w2,
                              const float* __restrict__ b2, int* __restrict__ eidx,
                              int* __restrict__ cnt, int* __restrict__ done,
                              int* __restrict__ offs, int* __restrict__ cur) {
  const int tid = threadIdx.x, lane = tid & 63, wv = tid >> 6;
  const int t = blockIdx.x * 4 + wv;
  const float* hr = hbuf + (size_t)t * D_DIM;
  float4 h0 = *(const float4*)(hr + lane * 8);
  float4 h1 = *(const float4*)(hr + lane * 8 + 4);
  float p[8] = {0, 0, 0, 0, 0, 0, 0, 0};
  const float* wr = w2 + (size_t)lane * 8 * 8;
  float hv[8] = {h0.x, h0.y, h0.z, h0.w, h1.x, h1.y, h1.z, h1.w};
#pragma unroll
  for (int j = 0; j < 8; ++j) {
    float4 wa = *(const float4*)(wr + j * 8);
    float4 wb = *(const float4*)(wr + j * 8 + 4);
    p[0] += hv[j] * wa.x; p[1] += hv[j] * wa.y; p[2] += hv[j] * wa.z; p[3] += hv[j] * wa.w;
    p[4] += hv[j] * wb.x; p[5] += hv[j] * wb.y; p[6] += hv[j] * wb.z; p[7] += hv[j] * wb.w;
  }
#pragma unroll
  for (int o = 32; o > 0; o >>= 1) {
#pragma unroll
    for (int e = 0; e < 8; ++e) p[e] += __shfl_xor(p[e], o, 64);
  }
  if (lane == 0) {
    int best = 0;
    float bvv = p[0] + b2[0];
#pragma unroll
    for (int e = 1; e < 8; ++e) {
      float v = p[e] + b2[e];
      if (v > bvv) { bvv = v; best = e; }
    }
    eidx[t] = best;
    atomicAdd(&cnt[best], 1);
  }
  __syncthreads();
  if (tid == 0) {
    __threadfence();
    int tix = atomicAdd(done, 1);
    if (tix == (int)gridDim.x - 1) {
      int a = 0;
#pragma unroll
      for (int i = 0; i < 8; ++i) { offs[i] = a; cur[i] = a; a += cnt[i]; }
      offs[8] = a;
      __threadfence();
    }
  }
}

__global__ void scatter_perm(const int* __restrict__ eidx, int* __restrict__ cur,
                             int* __restrict__ perm) {
  int t = blockIdx.x * blockDim.x + threadIdx.x;
  if (t < N_TOK) {
    int p = atomicAdd(&cur[eidx[t]], 1);
    perm[p] = t;
  }
}

// -------- expert GEMM + (optional) fused transpose of next level's W --------
// BM=128 BN=128 BK=32, 512 thr (8 waves 2x4); blocks [0,576)=GEMM,
// [576,2624)=transpose W_next (FUSET=1).
// SPLIT=1: 3-pass fp16-split; epilogue writes ONLY next-level x hi/lo.
// SPLIT=0 (last level): 1-pass; dout = hw0*x1h + hw1*xh + hw2*out.
// SPLIT=1 buffer: Ah[0,4096) Al[4096,8192) Bh[8192,12288) Bl[12288,16384)
// SPLIT=0 buffer: Ah[0,4096) Bh[4096,8192)
template <int SPLIT, int FUSET>
__global__ __launch_bounds__(512, 4) void expert_gemm(
    const half_t* __restrict__ xh, const half_t* __restrict__ xl,
    const half_t* __restrict__ Wth, const half_t* __restrict__ Wtl,
    const float* __restrict__ bb, const float* __restrict__ asg,
    const int* __restrict__ perm, const int* __restrict__ offs,
    const float* __restrict__ hwp,
    float* __restrict__ dout, const half_t* __restrict__ x1h,
    half_t* __restrict__ xnh, half_t* __restrict__ xnl,
    const float* __restrict__ WbN, half_t* __restrict__ WthN, half_t* __restrict__ WtlN) {
  constexpr int BUF = SPLIT ? 16384 : 8192;
  constexpr int OBH = SPLIT ? 8192 : 4096;
  __shared__ __align__(16) half_t lds[2 * BUF];
  __shared__ int toks[128];
  const int tid = threadIdx.x;

  if (FUSET && (int)blockIdx.x >= 576) {
    // 512-thread 64x64 transpose+cvt of next level's W_base
    float* tile = (float*)lds;  // [64][65]
    const int tb = (int)blockIdx.x - 576;
    const int bx = tb & 15, by = (tb >> 4) & 15, bz = tb >> 8;
    const size_t zo = (size_t)bz * H_DIM * H_DIM;
    const int rt = bx * 64, ct = by * 64;
    const int r = tid >> 3, c0 = (tid & 7) * 8;
    const float* p = WbN + zo + (size_t)(rt + r) * H_DIM + ct + c0;
    float4 va = *(const float4*)p;
    float4 vb = *(const float4*)(p + 4);
    tile[r * 65 + c0 + 0] = va.x; tile[r * 65 + c0 + 1] = va.y;
    tile[r * 65 + c0 + 2] = va.z; tile[r * 65 + c0 + 3] = va.w;
    tile[r * 65 + c0 + 4] = vb.x; tile[r * 65 + c0 + 5] = vb.y;
    tile[r * 65 + c0 + 6] = vb.z; tile[r * 65 + c0 + 7] = vb.w;
    __syncthreads();
    const int nl = tid >> 3, k0 = (tid & 7) * 8;
    half8 hvv, lvv;
#pragma unroll
    for (int i = 0; i < 8; ++i) {
      float v = tile[(k0 + i) * 65 + nl];
      half_t h = (half_t)v;
      hvv[i] = h;
      lvv[i] = (half_t)((v - (float)h) * 2048.f);
    }
    half_t* dst = WthN + zo + (size_t)(ct + nl) * H_DIM + rt + k0;
    *(half8*)dst = hvv;
    if (WtlN) {
      half_t* dl = WtlN + zo + (size_t)(ct + nl) * H_DIM + rt + k0;
      *(half8*)dl = lvv;
    }
    return;
  }

  // ---- GEMM: bid in [0,576), XCD-chunked (72 lids/XCD = 9 tok-tiles x 8 N) ----
  const int lid = ((int)blockIdx.x & 7) * 72 + ((int)blockIdx.x >> 3);
  const int byn = lid & 7;
  const int bxt = lid >> 3;
  int e = -1, base = 0, nrows = 0, acc_t = 0;
#pragma unroll
  for (int i = 0; i < 8; ++i) {
    int s = offs[i], t2 = offs[i + 1];
    int ntl = (t2 - s + 127) >> 7;
    if (e < 0 && bxt < acc_t + ntl) {
      e = i;
      base = s + (bxt - acc_t) * 128;
      nrows = t2 - base;
      if (nrows > 128) nrows = 128;
    }
    acc_t += ntl;
  }
  if (e < 0) return;
  if (tid < 128) toks[tid] = (tid < nrows) ? perm[base + tid] : perm[base];
  __syncthreads();
  const int arow = tid >> 2;
  const int skc = (((tid & 3) ^ ((tid >> 2) & 3) ^ ((tid >> 4) & 3)) * 8);
  const int tokA = toks[arow];
  const half_t* gAh = xh + (size_t)tokA * H_DIM + skc;
  const half_t* gAl = SPLIT ? (xl + (size_t)tokA * H_DIM + skc) : nullptr;
  const size_t bg = (size_t)e * H_DIM * H_DIM + (size_t)(byn * 128 + arow) * H_DIM + skc;
  const half_t* gBh = Wth + bg;
  const half_t* gBl = SPLIT ? (Wtl + bg) : nullptr;

  f32x4 accM[4][2], accX[4][2];
#pragma unroll
  for (int m = 0; m < 4; ++m)
#pragma unroll
    for (int n = 0; n < 2; ++n) {
      accM[m][n] = {0.f, 0.f, 0.f, 0.f};
      accX[m][n] = {0.f, 0.f, 0.f, 0.f};
    }

  const int lane = tid & 63, wv = tid >> 6, wm = wv >> 2, wn = wv & 3;
  const int fr = lane & 15, fg = lane >> 4;
  const int fgs = fg ^ ((fr & 3) ^ ((fr >> 2) & 3));
  const int aoff = (wm * 64 + fr) * 32 + fgs * 8;
  const int boff = OBH + (wn * 32 + fr) * 32 + fgs * 8;

#define E_STAGE(bo, kk) do { \
    const int go_ = (kk) * 32; \
    gload_lds16(gAh + go_, lds + (bo) + tid * 8); \
    gload_lds16(gBh + go_, lds + (bo) + OBH + tid * 8); \
    if (SPLIT) { \
      gload_lds16(gAl + go_, lds + (bo) + 4096 + tid * 8); \
      gload_lds16(gBl + go_, lds + (bo) + OBH + 4096 + tid * 8); \
    } \
  } while (0)

  E_STAGE(0, 0);
  for (int k = 0; k < 32; ++k) {
    if (k + 1 < 32) E_STAGE(((k + 1) & 1) * BUF, k + 1);
    if (k < 31) { if (SPLIT) { WAITV4; } else { WAITV2; } } else { WAITV0; }
    SCHEDB;
    RAWBAR;
    SCHEDB;
    const int cb = (k & 1) * BUF;
    half8 a_h[4], b_h[2], a_l[4], b_l[2];
#pragma unroll
    for (int m = 0; m < 4; ++m) {
      a_h[m] = *(const half8*)&lds[cb + aoff + m * 512];
      if (SPLIT) a_l[m] = *(const half8*)&lds[cb + 4096 + aoff + m * 512];
    }
#pragma unroll
    for (int n = 0; n < 2; ++n) {
      b_h[n] = *(const half8*)&lds[cb + boff + n * 512];
      if (SPLIT) b_l[n] = *(const half8*)&lds[cb + 4096 + boff + n * 512];
    }
    __builtin_amdgcn_s_setprio(1);
#pragma unroll
    for (int m = 0; m < 4; ++m)
#pragma unroll
      for (int n = 0; n < 2; ++n) {
        accM[m][n] = __builtin_amdgcn_mfma_f32_16x16x32_f16(a_h[m], b_h[n], accM[m][n], 0, 0, 0);
        if (SPLIT) {
          accX[m][n] = __builtin_amdgcn_mfma_f32_16x16x32_f16(a_h[m], b_l[n], accX[m][n], 0, 0, 0);
          accX[m][n] = __builtin_amdgcn_mfma_f32_16x16x32_f16(a_l[m], b_h[n], accX[m][n], 0, 0, 0);
        }
      }
    __builtin_amdgcn_s_setprio(0);
    SCHEDB;
    RAWBAR;
    SCHEDB;
  }
#undef E_STAGE

  const float ae = asg[e];
  const float hw0 = hwp[0], hw1 = hwp[1], hw2 = hwp[2];
  const float inv = 1.0f / 2048.0f;
#pragma unroll
  for (int m = 0; m < 4; ++m) {
    const int rl0 = wm * 64 + m * 16 + fg * 4;
#pragma unroll
    for (int n = 0; n < 2; ++n) {
      const int col = byn * 128 + wn * 32 + n * 16 + fr;
      const float bbv = bb[(size_t)e * H_DIM + col];
#pragma unroll
      for (int r = 0; r < 4; ++r) {
        const int rl = rl0 + r;
        if (rl < nrows) {
          const int tok = toks[rl];
          float s = accM[m][n][r] + bbv;
          if (SPLIT) s += accX[m][n][r] * inv;
          const float o = ae * s;
          const size_t idx = (size_t)tok * H_DIM + col;
          if (SPLIT) {
            half_t hv = (half_t)o;
            xnh[idx] = hv;
            xnl[idx] = (half_t)((o - (float)hv) * 2048.f);
          } else {
            dout[idx] = hw0 * (float)x1h[idx] + hw1 * (float)xh[idx] + hw2 * o;
          }
        }
      }
    }
  }
}

extern "C" void kernel_launch(void* const* d_in, const int* in_sizes, int n_in,
                              void* d_out, int out_size, void* d_ws, size_t ws_size,
                              hipStream_t stream) {
  const float* hs  = (const float*)d_in[0];   // (2,4096,1024)
  const float* w1  = (const float*)d_in[1];   // (3,1024,512)
  const float* b1  = (const float*)d_in[2];   // (3,512)
  const float* w2  = (const float*)d_in[3];   // (3,512,8)
  const float* b2  = (const float*)d_in[4];   // (3,8)
  const float* lea = (const float*)d_in[5];   // (3,8)
  const float* hww = (const float*)d_in[6];   // (3,)
  const float* Wb  = (const float*)d_in[7];   // (3,8,1024,1024)
  const float* bb  = (const float*)d_in[8];   // (3,8,1024)
  float* outp = (float*)d_out;

  char* ws = (char*)d_ws;
  size_t off = 0;
  half_t* WthA = (half_t*)(ws + off); off += (size_t)NE * H_DIM * H_DIM * 2;
  half_t* WtlA = (half_t*)(ws + off); off += (size_t)NE * H_DIM * H_DIM * 2;
  half_t* WthB = (half_t*)(ws + off); off += (size_t)NE * H_DIM * H_DIM * 2;
  half_t* WtlB = (half_t*)(ws + off); off += (size_t)NE * H_DIM * H_DIM * 2;
  half_t* w1th = (half_t*)(ws + off); off += (size_t)NL * D_DIM * H_DIM * 2;
  half_t* w1tl = (half_t*)(ws + off); off += (size_t)NL * D_DIM * H_DIM * 2;
  half_t* xh0  = (half_t*)(ws + off); off += (size_t)N_TOK * H_DIM * 2;
  half_t* xl0  = (half_t*)(ws + off); off += (size_t)N_TOK * H_DIM * 2;
  half_t* xh1  = (half_t*)(ws + off); off += (size_t)N_TOK * H_DIM * 2;
  half_t* xl1  = (half_t*)(ws + off); off += (size_t)N_TOK * H_DIM * 2;
  float*  hbuf = (float*)(ws + off);  off += (size_t)N_TOK * D_DIM * 4;
  int*    eidx = (int*)(ws + off);    off += (size_t)N_TOK * 4;
  int*    perm = (int*)(ws + off);    off += (size_t)N_TOK * 4;
  int*    cnt  = (int*)(ws + off);    off += (size_t)NL * NE * 4;
  int*    offs = (int*)(ws + off);    off += (size_t)NL * (NE + 1) * 4;
  int*    cur  = (int*)(ws + off);    off += (size_t)NL * NE * 4;
  int*    done = (int*)(ws + off);    off += (size_t)NL * 4;
  float*  hwp  = (float*)(ws + off);  off += 16;

  prep<<<3457, 256, 0, stream>>>(hww, hwp, cnt, done, w1, w1th, w1tl,
                                 Wb, WthA, WtlA, hs, xh0, xl0);

  for (int l = 0; l < NL; ++l) {
    const half_t* xch = (l & 1) ? xh1 : xh0;
    const half_t* xcl = (l & 1) ? xl1 : xl0;
    half_t* xnh = (l & 1) ? xh0 : xh1;
    half_t* xnl = (l & 1) ? xl0 : xl1;
    routing_gemm<<<256, 512, 0, stream>>>(
        xch, xcl, w1th + (size_t)l * D_DIM * H_DIM, w1tl + (size_t)l * D_DIM * H_DIM,
        b1 + l * D_DIM, hbuf);
    logits_argmax<<<N_TOK / 4, 256, 0, stream>>>(
        hbuf, w2 + (size_t)l * D_DIM * NE, b2 + l * NE, eidx,
        cnt + l * NE, done + l, offs + l * (NE + 1), cur + l * NE);
    scatter_perm<<<N_TOK / 256, 256, 0, stream>>>(eidx, cur + l * NE, perm);
    if (l == 0) {
      expert_gemm<1, 1><<<2624, 512, 0, stream>>>(
          xch, xcl, WthA, WtlA, bb + (size_t)l * NE * H_DIM,
          lea + l * NE, perm, offs + l * (NE + 1), hwp,
          (float*)nullptr, (const half_t*)nullptr, xnh, xnl,
          Wb + (size_t)1 * NE * H_DIM * H_DIM, WthB, WtlB);
    } else if (l == 1) {
      expert_gemm<1, 1><<<2624, 512, 0, stream>>>(
          xch, xcl, WthB, WtlB, bb + (size_t)l * NE * H_DIM,
          lea + l * NE, perm, offs + l * (NE + 1), hwp,
          (float*)nullptr, (const half_t*)nullptr, xnh, xnl,
          Wb + (size_t)2 * NE * H_DIM * H_DIM, WthA, (half_t*)nullptr);
    } else {
      // last level: xch = x2 (xh0); x1 hi lives in xh1
      expert_gemm<0, 0><<<576, 512, 0, stream>>>(
          xch, (const half_t*)nullptr, WthA, (const half_t*)nullptr,
          bb + (size_t)l * NE * H_DIM,
          lea + l * NE, perm, offs + l * (NE + 1), hwp,
          outp, xh1, (half_t*)nullptr, (half_t*)nullptr,
          (const float*)nullptr, (half_t*)nullptr, (half_t*)nullptr);
    }
  }
}

// Round 11
// 531.687 us; speedup vs baseline: 1.6544x; 1.5423x over previous
//
#include <hip/hip_runtime.h>
#include <stdint.h>

typedef _Float16 half_t;
typedef __attribute__((ext_vector_type(4))) _Float16 half4;
typedef __attribute__((ext_vector_type(8))) _Float16 half8;
typedef __attribute__((ext_vector_type(4))) float f32x4;

#define N_TOK 8192
#define H_DIM 1024
#define D_DIM 512
#define NE 8
#define NL 3

#define WAITV4 asm volatile("s_waitcnt vmcnt(4)" ::: "memory")
#define WAITV2 asm volatile("s_waitcnt vmcnt(2)" ::: "memory")
#define WAITV0 asm volatile("s_waitcnt vmcnt(0)" ::: "memory")
#define SCHEDB __builtin_amdgcn_sched_barrier(0)
#define RAWBAR __builtin_amdgcn_s_barrier()

// -------- async global->LDS, 16B per lane, linear dest --------
__device__ __forceinline__ void gload_lds16(const half_t* g, half_t* l) {
  __builtin_amdgcn_global_load_lds(
      (const __attribute__((address_space(1))) unsigned int*)g,
      (__attribute__((address_space(3))) unsigned int*)l, 16, 0, 0);
}

// -------- 256-thread 64x64 transpose+cvt tile (tile pitch 65 floats) --------
__device__ __forceinline__ void tr_tile_256(
    const float* src, half_t* oh, half_t* ol, int R, int C,
    int bx, int by, int tid, float* tile) {
  const int rt = bx * 64, ct = by * 64;
  const int r = tid >> 2, c0 = (tid & 3) * 16;
  const float* p = src + (size_t)(rt + r) * C + ct + c0;
#pragma unroll
  for (int q = 0; q < 4; ++q) {
    float4 v = *(const float4*)(p + q * 4);
    tile[r * 65 + c0 + q * 4 + 0] = v.x;
    tile[r * 65 + c0 + q * 4 + 1] = v.y;
    tile[r * 65 + c0 + q * 4 + 2] = v.z;
    tile[r * 65 + c0 + q * 4 + 3] = v.w;
  }
  __syncthreads();
  const int nl = tid >> 2, k0 = (tid & 3) * 16;
  half8 hv0, hv1, lv0, lv1;
#pragma unroll
  for (int i = 0; i < 16; ++i) {
    float v = tile[(k0 + i) * 65 + nl];
    half_t h = (half_t)v;
    half_t lo = (half_t)((v - (float)h) * 2048.f);
    if (i < 8) { hv0[i] = h; lv0[i] = lo; } else { hv1[i - 8] = h; lv1[i - 8] = lo; }
  }
  half_t* dst = oh + (size_t)(ct + nl) * R + rt + k0;
  *(half8*)dst = hv0;
  *(half8*)(dst + 8) = hv1;
  if (ol) {
    half_t* dl = ol + (size_t)(ct + nl) * R + rt + k0;
    *(half8*)dl = lv0;
    *(half8*)(dl + 8) = lv1;
  }
}

// -------- prep: init + w1 transpose + W[0] transpose + cvt_x, one kernel --------
__global__ __launch_bounds__(256) void prep(
    const float* __restrict__ hww, float* __restrict__ hwp,
    int* __restrict__ cnt, int* __restrict__ done,
    const float* __restrict__ w1, half_t* __restrict__ w1th, half_t* __restrict__ w1tl,
    const float* __restrict__ Wb0, half_t* __restrict__ Wth0, half_t* __restrict__ Wtl0,
    const float* __restrict__ hs, half_t* __restrict__ xh0, half_t* __restrict__ xl0) {
  __shared__ float tile[64 * 65];
  const int bid = blockIdx.x, tid = threadIdx.x;
  if (bid == 0) {
    if (tid < NL * NE) cnt[tid] = 0;
    if (tid < NL) done[tid] = 0;
    if (tid == 0) {
      float m = fmaxf(fmaxf(hww[0], hww[1]), hww[2]);
      float e0 = expf(hww[0] - m), e1 = expf(hww[1] - m), e2 = expf(hww[2] - m);
      float s = e0 + e1 + e2;
      hwp[0] = e0 / s; hwp[1] = e1 / s; hwp[2] = e2 / s;
    }
    return;
  }
  if (bid < 385) {
    const int t = bid - 1;
    const int bx = t & 15, by = (t >> 4) & 7, bz = t >> 7;
    tr_tile_256(w1 + (size_t)bz * H_DIM * D_DIM,
                w1th + (size_t)bz * D_DIM * H_DIM,
                w1tl + (size_t)bz * D_DIM * H_DIM,
                H_DIM, D_DIM, bx, by, tid, tile);
    return;
  }
  if (bid < 2433) {
    const int t = bid - 385;
    const int bx = t & 15, by = (t >> 4) & 15, bz = t >> 8;
    tr_tile_256(Wb0 + (size_t)bz * H_DIM * H_DIM,
                Wth0 + (size_t)bz * H_DIM * H_DIM,
                Wtl0 + (size_t)bz * H_DIM * H_DIM,
                H_DIM, H_DIM, bx, by, tid, tile);
    return;
  }
  int i = (bid - 2433) * 256 + tid;
  const int total = N_TOK * H_DIM / 4, stride = 1024 * 256;
  for (; i < total; i += stride) {
    float4 v = ((const float4*)hs)[i];
    float vv[4] = {v.x, v.y, v.z, v.w};
    half4 hv, lv;
#pragma unroll
    for (int j = 0; j < 4; ++j) {
      half_t h = (half_t)vv[j];
      hv[j] = h;
      lv[j] = (half_t)((vv[j] - (float)h) * 2048.f);
    }
    ((half4*)xh0)[i] = hv;
    ((half4*)xl0)[i] = lv;
  }
}

// -------- router GEMM: h = relu(x @ w1 + b1), fp16-split 3-pass MFMA --------
// BM=128 BN=128 BK=32, 512 thr (8 waves 2x4), 2-buf counted vmcnt, swizzled LDS.
__global__ __launch_bounds__(512, 4) void routing_gemm(
    const half_t* __restrict__ xh, const half_t* __restrict__ xl,
    const half_t* __restrict__ wh, const half_t* __restrict__ wl,
    const float* __restrict__ b1, float* __restrict__ hout) {
  __shared__ __align__(16) half_t lds[2 * 16384];
  const int tid = threadIdx.x;
  const int lane = tid & 63, wv = tid >> 6;
  const int wm = wv >> 2, wn = wv & 3;
  const int lid = ((int)blockIdx.x & 7) * 32 + ((int)blockIdx.x >> 3);
  const int nt = lid & 3, mt = lid >> 2;

  const int srow = tid >> 2;
  const int skc = (((tid & 3) ^ ((tid >> 2) & 3) ^ ((tid >> 4) & 3)) * 8);
  const half_t* gAh = xh + (size_t)(mt * 128 + srow) * H_DIM + skc;
  const half_t* gAl = xl + (size_t)(mt * 128 + srow) * H_DIM + skc;
  const half_t* gBh = wh + (size_t)(nt * 128 + srow) * H_DIM + skc;
  const half_t* gBl = wl + (size_t)(nt * 128 + srow) * H_DIM + skc;

  f32x4 accM[4][2], accX[4][2];
#pragma unroll
  for (int m = 0; m < 4; ++m)
#pragma unroll
    for (int n = 0; n < 2; ++n) {
      accM[m][n] = {0.f, 0.f, 0.f, 0.f};
      accX[m][n] = {0.f, 0.f, 0.f, 0.f};
    }

  const int fr = lane & 15, fg = lane >> 4;
  const int fgs = fg ^ ((fr & 3) ^ ((fr >> 2) & 3));
  const int aoff = (wm * 64 + fr) * 32 + fgs * 8;
  const int boff = 8192 + (wn * 32 + fr) * 32 + fgs * 8;

#define R_STAGE(bo, kk) do { \
    const int go_ = (kk) * 32; \
    gload_lds16(gAh + go_, lds + (bo) + tid * 8); \
    gload_lds16(gAl + go_, lds + (bo) + 4096 + tid * 8); \
    gload_lds16(gBh + go_, lds + (bo) + 8192 + tid * 8); \
    gload_lds16(gBl + go_, lds + (bo) + 12288 + tid * 8); \
  } while (0)

  R_STAGE(0, 0);
  for (int k = 0; k < 32; ++k) {
    if (k + 1 < 32) R_STAGE(((k + 1) & 1) * 16384, k + 1);
    if (k < 31) { WAITV4; } else { WAITV0; }
    SCHEDB;
    RAWBAR;
    SCHEDB;
    const int cb = (k & 1) * 16384;
    half8 a_h[4], a_l[4], b_h[2], b_l[2];
#pragma unroll
    for (int m = 0; m < 4; ++m) {
      a_h[m] = *(const half8*)&lds[cb + aoff + m * 512];
      a_l[m] = *(const half8*)&lds[cb + 4096 + aoff + m * 512];
    }
#pragma unroll
    for (int n = 0; n < 2; ++n) {
      b_h[n] = *(const half8*)&lds[cb + boff + n * 512];
      b_l[n] = *(const half8*)&lds[cb + 4096 + boff + n * 512];
    }
    __builtin_amdgcn_s_setprio(1);
#pragma unroll
    for (int m = 0; m < 4; ++m)
#pragma unroll
      for (int n = 0; n < 2; ++n) {
        accM[m][n] = __builtin_amdgcn_mfma_f32_16x16x32_f16(a_h[m], b_h[n], accM[m][n], 0, 0, 0);
        accX[m][n] = __builtin_amdgcn_mfma_f32_16x16x32_f16(a_h[m], b_l[n], accX[m][n], 0, 0, 0);
        accX[m][n] = __builtin_amdgcn_mfma_f32_16x16x32_f16(a_l[m], b_h[n], accX[m][n], 0, 0, 0);
      }
    __builtin_amdgcn_s_setprio(0);
    SCHEDB;
    RAWBAR;
    SCHEDB;
  }
#undef R_STAGE

  const float inv = 1.0f / 2048.0f;
#pragma unroll
  for (int m = 0; m < 4; ++m) {
    const int row0 = mt * 128 + wm * 64 + m * 16 + fg * 4;
#pragma unroll
    for (int n = 0; n < 2; ++n) {
      const int col = nt * 128 + wn * 32 + n * 16 + fr;
      const float bv = b1[col];
#pragma unroll
      for (int r = 0; r < 4; ++r) {
        float v = accM[m][n][r] + accX[m][n][r] * inv + bv;
        hout[(size_t)(row0 + r) * D_DIM + col] = fmaxf(v, 0.f);
      }
    }
  }
}

// -------- logits + argmax; 64 blocks, 32 tokens/wave, LDS histogram --------
// w2 register-cached per wave; per-token reduction order identical to prior
// rounds (bit-identical logits). 8 global atomics/block; last block scans.
__global__ __launch_bounds__(256) void logits_argmax(
    const float* __restrict__ hbuf, const float* __restrict__ w2,
    const float* __restrict__ b2, int* __restrict__ eidx,
    int* __restrict__ cnt, int* __restrict__ done,
    int* __restrict__ offs, int* __restrict__ cur) {
  __shared__ int hist[8];
  const int tid = threadIdx.x, lane = tid & 63, wv = tid >> 6;
  if (tid < 8) hist[tid] = 0;
  __syncthreads();
  // preload w2 rows lane*8 .. lane*8+7 (64 floats) into registers
  float w2r[64];
  const float* wr = w2 + (size_t)lane * 64;
#pragma unroll
  for (int i = 0; i < 16; ++i) {
    float4 v = *(const float4*)(wr + i * 4);
    w2r[i * 4 + 0] = v.x; w2r[i * 4 + 1] = v.y;
    w2r[i * 4 + 2] = v.z; w2r[i * 4 + 3] = v.w;
  }
  float b2r[8];
#pragma unroll
  for (int e = 0; e < 8; ++e) b2r[e] = b2[e];

  const int t0 = (int)blockIdx.x * 128 + wv * 32;
  for (int it = 0; it < 32; ++it) {
    const int t = t0 + it;
    const float* hr = hbuf + (size_t)t * D_DIM + lane * 8;
    float4 h0 = *(const float4*)hr;
    float4 h1 = *(const float4*)(hr + 4);
    float hv[8] = {h0.x, h0.y, h0.z, h0.w, h1.x, h1.y, h1.z, h1.w};
    float p[8] = {0, 0, 0, 0, 0, 0, 0, 0};
#pragma unroll
    for (int j = 0; j < 8; ++j)
#pragma unroll
      for (int e = 0; e < 8; ++e) p[e] += hv[j] * w2r[j * 8 + e];
#pragma unroll
    for (int o = 32; o > 0; o >>= 1) {
#pragma unroll
      for (int e = 0; e < 8; ++e) p[e] += __shfl_xor(p[e], o, 64);
    }
    if (lane == 0) {
      int best = 0;
      float bvv = p[0] + b2r[0];
#pragma unroll
      for (int e = 1; e < 8; ++e) {
        float v = p[e] + b2r[e];
        if (v > bvv) { bvv = v; best = e; }
      }
      eidx[t] = best;
      atomicAdd(&hist[best], 1);
    }
  }
  __syncthreads();
  if (tid < 8) {
    int h = hist[tid];
    if (h > 0) atomicAdd(&cnt[tid], h);
  }
  __syncthreads();
  if (tid == 0) {
    __threadfence();
    int tix = atomicAdd(done, 1);
    if (tix == (int)gridDim.x - 1) {
      __threadfence();
      int a = 0;
#pragma unroll
      for (int i = 0; i < 8; ++i) { offs[i] = a; cur[i] = a; a += cnt[i]; }
      offs[8] = a;
      __threadfence();
    }
  }
}

// -------- scatter: ballot-ranked, 8 reservation atomics per block --------
__global__ __launch_bounds__(256) void scatter_perm(
    const int* __restrict__ eidx, int* __restrict__ cur, int* __restrict__ perm) {
  __shared__ int wcnt[4][8];
  __shared__ int wbase[4][8];
  __shared__ int bbase[8];
  const int tid = threadIdx.x, lane = tid & 63, wv = tid >> 6;
  const int t = (int)blockIdx.x * 256 + tid;
  const int e = eidx[t];
  int rank = 0;
#pragma unroll
  for (int i = 0; i < 8; ++i) {
    unsigned long long m = __ballot(e == i);
    if (i == e) rank = __popcll(m & ((1ull << lane) - 1ull));
    if (lane == 0) wcnt[wv][i] = (int)__popcll(m);
  }
  __syncthreads();
  if (tid < 8) {
    int a = 0;
#pragma unroll
    for (int w = 0; w < 4; ++w) { wbase[w][tid] = a; a += wcnt[w][tid]; }
    bbase[tid] = atomicAdd(&cur[tid], a);
  }
  __syncthreads();
  perm[bbase[e] + wbase[wv][e] + rank] = t;
}

// -------- expert GEMM + (optional) fused transpose of next level's W --------
// BM=128 BN=128 BK=32, 512 thr (8 waves 2x4); blocks [0,576)=GEMM,
// [576,2624)=transpose W_next (FUSET=1).
// SPLIT=1: 3-pass fp16-split; epilogue writes ONLY next-level x hi/lo.
// SPLIT=0 (last level): 1-pass; dout = hw0*x1h + hw1*xh + hw2*out.
template <int SPLIT, int FUSET>
__global__ __launch_bounds__(512, 4) void expert_gemm(
    const half_t* __restrict__ xh, const half_t* __restrict__ xl,
    const half_t* __restrict__ Wth, const half_t* __restrict__ Wtl,
    const float* __restrict__ bb, const float* __restrict__ asg,
    const int* __restrict__ perm, const int* __restrict__ offs,
    const float* __restrict__ hwp,
    float* __restrict__ dout, const half_t* __restrict__ x1h,
    half_t* __restrict__ xnh, half_t* __restrict__ xnl,
    const float* __restrict__ WbN, half_t* __restrict__ WthN, half_t* __restrict__ WtlN) {
  constexpr int BUF = SPLIT ? 16384 : 8192;
  constexpr int OBH = SPLIT ? 8192 : 4096;
  __shared__ __align__(16) half_t lds[2 * BUF];
  __shared__ int toks[128];
  const int tid = threadIdx.x;

  if (FUSET && (int)blockIdx.x >= 576) {
    float* tile = (float*)lds;  // [64][65]
    const int tb = (int)blockIdx.x - 576;
    const int bx = tb & 15, by = (tb >> 4) & 15, bz = tb >> 8;
    const size_t zo = (size_t)bz * H_DIM * H_DIM;
    const int rt = bx * 64, ct = by * 64;
    const int r = tid >> 3, c0 = (tid & 7) * 8;
    const float* p = WbN + zo + (size_t)(rt + r) * H_DIM + ct + c0;
    float4 va = *(const float4*)p;
    float4 vb = *(const float4*)(p + 4);
    tile[r * 65 + c0 + 0] = va.x; tile[r * 65 + c0 + 1] = va.y;
    tile[r * 65 + c0 + 2] = va.z; tile[r * 65 + c0 + 3] = va.w;
    tile[r * 65 + c0 + 4] = vb.x; tile[r * 65 + c0 + 5] = vb.y;
    tile[r * 65 + c0 + 6] = vb.z; tile[r * 65 + c0 + 7] = vb.w;
    __syncthreads();
    const int nl = tid >> 3, k0 = (tid & 7) * 8;
    half8 hvv, lvv;
#pragma unroll
    for (int i = 0; i < 8; ++i) {
      float v = tile[(k0 + i) * 65 + nl];
      half_t h = (half_t)v;
      hvv[i] = h;
      lvv[i] = (half_t)((v - (float)h) * 2048.f);
    }
    half_t* dst = WthN + zo + (size_t)(ct + nl) * H_DIM + rt + k0;
    *(half8*)dst = hvv;
    if (WtlN) {
      half_t* dl = WtlN + zo + (size_t)(ct + nl) * H_DIM + rt + k0;
      *(half8*)dl = lvv;
    }
    return;
  }

  // ---- GEMM: bid in [0,576), XCD-chunked (72 lids/XCD = 9 tok-tiles x 8 N) ----
  const int lid = ((int)blockIdx.x & 7) * 72 + ((int)blockIdx.x >> 3);
  const int byn = lid & 7;
  const int bxt = lid >> 3;
  int e = -1, base = 0, nrows = 0, acc_t = 0;
#pragma unroll
  for (int i = 0; i < 8; ++i) {
    int s = offs[i], t2 = offs[i + 1];
    int ntl = (t2 - s + 127) >> 7;
    if (e < 0 && bxt < acc_t + ntl) {
      e = i;
      base = s + (bxt - acc_t) * 128;
      nrows = t2 - base;
      if (nrows > 128) nrows = 128;
    }
    acc_t += ntl;
  }
  if (e < 0) return;
  if (tid < 128) toks[tid] = (tid < nrows) ? perm[base + tid] : perm[base];
  __syncthreads();
  const int arow = tid >> 2;
  const int skc = (((tid & 3) ^ ((tid >> 2) & 3) ^ ((tid >> 4) & 3)) * 8);
  const int tokA = toks[arow];
  const half_t* gAh = xh + (size_t)tokA * H_DIM + skc;
  const half_t* gAl = SPLIT ? (xl + (size_t)tokA * H_DIM + skc) : nullptr;
  const size_t bg = (size_t)e * H_DIM * H_DIM + (size_t)(byn * 128 + arow) * H_DIM + skc;
  const half_t* gBh = Wth + bg;
  const half_t* gBl = SPLIT ? (Wtl + bg) : nullptr;

  f32x4 accM[4][2], accX[4][2];
#pragma unroll
  for (int m = 0; m < 4; ++m)
#pragma unroll
    for (int n = 0; n < 2; ++n) {
      accM[m][n] = {0.f, 0.f, 0.f, 0.f};
      accX[m][n] = {0.f, 0.f, 0.f, 0.f};
    }

  const int lane = tid & 63, wv = tid >> 6, wm = wv >> 2, wn = wv & 3;
  const int fr = lane & 15, fg = lane >> 4;
  const int fgs = fg ^ ((fr & 3) ^ ((fr >> 2) & 3));
  const int aoff = (wm * 64 + fr) * 32 + fgs * 8;
  const int boff = OBH + (wn * 32 + fr) * 32 + fgs * 8;

#define E_STAGE(bo, kk) do { \
    const int go_ = (kk) * 32; \
    gload_lds16(gAh + go_, lds + (bo) + tid * 8); \
    gload_lds16(gBh + go_, lds + (bo) + OBH + tid * 8); \
    if (SPLIT) { \
      gload_lds16(gAl + go_, lds + (bo) + 4096 + tid * 8); \
      gload_lds16(gBl + go_, lds + (bo) + OBH + 4096 + tid * 8); \
    } \
  } while (0)

  E_STAGE(0, 0);
  for (int k = 0; k < 32; ++k) {
    if (k + 1 < 32) E_STAGE(((k + 1) & 1) * BUF, k + 1);
    if (k < 31) { if (SPLIT) { WAITV4; } else { WAITV2; } } else { WAITV0; }
    SCHEDB;
    RAWBAR;
    SCHEDB;
    const int cb = (k & 1) * BUF;
    half8 a_h[4], b_h[2], a_l[4], b_l[2];
#pragma unroll
    for (int m = 0; m < 4; ++m) {
      a_h[m] = *(const half8*)&lds[cb + aoff + m * 512];
      if (SPLIT) a_l[m] = *(const half8*)&lds[cb + 4096 + aoff + m * 512];
    }
#pragma unroll
    for (int n = 0; n < 2; ++n) {
      b_h[n] = *(const half8*)&lds[cb + boff + n * 512];
      if (SPLIT) b_l[n] = *(const half8*)&lds[cb + 4096 + boff + n * 512];
    }
    __builtin_amdgcn_s_setprio(1);
#pragma unroll
    for (int m = 0; m < 4; ++m)
#pragma unroll
      for (int n = 0; n < 2; ++n) {
        accM[m][n] = __builtin_amdgcn_mfma_f32_16x16x32_f16(a_h[m], b_h[n], accM[m][n], 0, 0, 0);
        if (SPLIT) {
          accX[m][n] = __builtin_amdgcn_mfma_f32_16x16x32_f16(a_h[m], b_l[n], accX[m][n], 0, 0, 0);
          accX[m][n] = __builtin_amdgcn_mfma_f32_16x16x32_f16(a_l[m], b_h[n], accX[m][n], 0, 0, 0);
        }
      }
    __builtin_amdgcn_s_setprio(0);
    SCHEDB;
    RAWBAR;
    SCHEDB;
  }
#undef E_STAGE

  const float ae = asg[e];
  const float hw0 = hwp[0], hw1 = hwp[1], hw2 = hwp[2];
  const float inv = 1.0f / 2048.0f;
#pragma unroll
  for (int m = 0; m < 4; ++m) {
    const int rl0 = wm * 64 + m * 16 + fg * 4;
#pragma unroll
    for (int n = 0; n < 2; ++n) {
      const int col = byn * 128 + wn * 32 + n * 16 + fr;
      const float bbv = bb[(size_t)e * H_DIM + col];
#pragma unroll
      for (int r = 0; r < 4; ++r) {
        const int rl = rl0 + r;
        if (rl < nrows) {
          const int tok = toks[rl];
          float s = accM[m][n][r] + bbv;
          if (SPLIT) s += accX[m][n][r] * inv;
          const float o = ae * s;
          const size_t idx = (size_t)tok * H_DIM + col;
          if (SPLIT) {
            half_t hv = (half_t)o;
            xnh[idx] = hv;
            xnl[idx] = (half_t)((o - (float)hv) * 2048.f);
          } else {
            dout[idx] = hw0 * (float)x1h[idx] + hw1 * (float)xh[idx] + hw2 * o;
          }
        }
      }
    }
  }
}

extern "C" void kernel_launch(void* const* d_in, const int* in_sizes, int n_in,
                              void* d_out, int out_size, void* d_ws, size_t ws_size,
                              hipStream_t stream) {
  const float* hs  = (const float*)d_in[0];   // (2,4096,1024)
  const float* w1  = (const float*)d_in[1];   // (3,1024,512)
  const float* b1  = (const float*)d_in[2];   // (3,512)
  const float* w2  = (const float*)d_in[3];   // (3,512,8)
  const float* b2  = (const float*)d_in[4];   // (3,8)
  const float* lea = (const float*)d_in[5];   // (3,8)
  const float* hww = (const float*)d_in[6];   // (3,)
  const float* Wb  = (const float*)d_in[7];   // (3,8,1024,1024)
  const float* bb  = (const float*)d_in[8];   // (3,8,1024)
  float* outp = (float*)d_out;

  char* ws = (char*)d_ws;
  size_t off = 0;
  half_t* WthA = (half_t*)(ws + off); off += (size_t)NE * H_DIM * H_DIM * 2;
  half_t* WtlA = (half_t*)(ws + off); off += (size_t)NE * H_DIM * H_DIM * 2;
  half_t* WthB = (half_t*)(ws + off); off += (size_t)NE * H_DIM * H_DIM * 2;
  half_t* WtlB = (half_t*)(ws + off); off += (size_t)NE * H_DIM * H_DIM * 2;
  half_t* w1th = (half_t*)(ws + off); off += (size_t)NL * D_DIM * H_DIM * 2;
  half_t* w1tl = (half_t*)(ws + off); off += (size_t)NL * D_DIM * H_DIM * 2;
  half_t* xh0  = (half_t*)(ws + off); off += (size_t)N_TOK * H_DIM * 2;
  half_t* xl0  = (half_t*)(ws + off); off += (size_t)N_TOK * H_DIM * 2;
  half_t* xh1  = (half_t*)(ws + off); off += (size_t)N_TOK * H_DIM * 2;
  half_t* xl1  = (half_t*)(ws + off); off += (size_t)N_TOK * H_DIM * 2;
  float*  hbuf = (float*)(ws + off);  off += (size_t)N_TOK * D_DIM * 4;
  int*    eidx = (int*)(ws + off);    off += (size_t)N_TOK * 4;
  int*    perm = (int*)(ws + off);    off += (size_t)N_TOK * 4;
  int*    cnt  = (int*)(ws + off);    off += (size_t)NL * NE * 4;
  int*    offs = (int*)(ws + off);    off += (size_t)NL * (NE + 1) * 4;
  int*    cur  = (int*)(ws + off);    off += (size_t)NL * NE * 4;
  int*    done = (int*)(ws + off);    off += (size_t)NL * 4;
  float*  hwp  = (float*)(ws + off);  off += 16;

  prep<<<3457, 256, 0, stream>>>(hww, hwp, cnt, done, w1, w1th, w1tl,
                                 Wb, WthA, WtlA, hs, xh0, xl0);

  for (int l = 0; l < NL; ++l) {
    const half_t* xch = (l & 1) ? xh1 : xh0;
    const half_t* xcl = (l & 1) ? xl1 : xl0;
    half_t* xnh = (l & 1) ? xh0 : xh1;
    half_t* xnl = (l & 1) ? xl0 : xl1;
    routing_gemm<<<256, 512, 0, stream>>>(
        xch, xcl, w1th + (size_t)l * D_DIM * H_DIM, w1tl + (size_t)l * D_DIM * H_DIM,
        b1 + l * D_DIM, hbuf);
    logits_argmax<<<64, 256, 0, stream>>>(
        hbuf, w2 + (size_t)l * D_DIM * NE, b2 + l * NE, eidx,
        cnt + l * NE, done + l, offs + l * (NE + 1), cur + l * NE);
    scatter_perm<<<N_TOK / 256, 256, 0, stream>>>(eidx, cur + l * NE, perm);
    if (l == 0) {
      expert_gemm<1, 1><<<2624, 512, 0, stream>>>(
          xch, xcl, WthA, WtlA, bb + (size_t)l * NE * H_DIM,
          lea + l * NE, perm, offs + l * (NE + 1), hwp,
          (float*)nullptr, (const half_t*)nullptr, xnh, xnl,
          Wb + (size_t)1 * NE * H_DIM * H_DIM, WthB, WtlB);
    } else if (l == 1) {
      expert_gemm<1, 1><<<2624, 512, 0, stream>>>(
          xch, xcl, WthB, WtlB, bb + (size_t)l * NE * H_DIM,
          lea + l * NE, perm, offs + l * (NE + 1), hwp,
          (float*)nullptr, (const half_t*)nullptr, xnh, xnl,
          Wb + (size_t)2 * NE * H_DIM * H_DIM, WthA, (half_t*)nullptr);
    } else {
      // last level: xch = x2 (xh0); x1 hi lives in xh1
      expert_gemm<0, 0><<<576, 512, 0, stream>>>(
          xch, (const half_t*)nullptr, WthA, (const half_t*)nullptr,
          bb + (size_t)l * NE * H_DIM,
          lea + l * NE, perm, offs + l * (NE + 1), hwp,
          outp, xh1, (half_t*)nullptr, (half_t*)nullptr,
          (const float*)nullptr, (half_t*)nullptr, (half_t*)nullptr);
    }
  }
}